// Round 1
// 115.318 us; speedup vs baseline: 1.0928x; 1.0928x over previous
//
#include <hip/hip_runtime.h>

#define Bn 4
#define Qn 1024
#define Kn 1024
#define Dd 256
#define Hh 64
#define Dv 256
#define TQ 16

typedef __attribute__((ext_vector_type(8))) short short8;
typedef __attribute__((ext_vector_type(4))) float floatx4;
typedef __attribute__((ext_vector_type(2))) float floatx2;

__device__ __forceinline__ floatx2 fma2(floatx2 a, floatx2 b, floatx2 c) {
    return __builtin_elementwise_fma(a, b, c);
}
__device__ __forceinline__ floatx2 mk2(float x, float y) {
    floatx2 r; r.x = x; r.y = y; return r;
}

__device__ __forceinline__ short f32_to_bf16(float x) {
    unsigned u = __float_as_uint(x);
    unsigned r = u + 0x7fffu + ((u >> 16) & 1u);   // RNE
    return (short)(r >> 16);
}
__device__ __forceinline__ float bf16_to_f32(short h) {
    return __uint_as_float(((unsigned)(unsigned short)h) << 16);
}

// Fused prep v4: projections via MFMA (split-bf16 hi/lo, 3 mfma per k-tile).
// R18 theory: the old VALU proj loop was load-latency serialized at 1
// wave/SIMD (~40us measured, vs 1.7us of FMA work). MFMA form: all 16
// X-loads issued upfront (one vmcnt wait), W staged once per block into LDS
// in B-fragment order (lane-linear ds_read_b128, conflict-free), 96 MFMAs
// per wave of deep ILP. Fragment layout identical to the proven attn AV
// path: A/B free-index = lane&15, k = (lane>>4)*8+j; C col = lane&15,
// row = (lane>>4)*4+reg.
//  blocks 0..127  : projections (blk>>6 = side; 64 rows/block, 16/wave)
//  blocks 128..255: V -> split-bf16 MFMA-A-fragment swizzle (unchanged)
__global__ __launch_bounds__(256) void prep_kernel(const float* __restrict__ Xq,
                                                   const float* __restrict__ Wq,
                                                   const float* __restrict__ Xk,
                                                   const float* __restrict__ Wk,
                                                   const float* __restrict__ V,
                                                   float* __restrict__ Eq,
                                                   float* __restrict__ Ekt,
                                                   short* __restrict__ Vhi,
                                                   short* __restrict__ Vlo) {
    __shared__ __align__(16) char smem[65536];   // proj: W frags hi/lo (64KB); V: tile (33.4KB)
    int t = threadIdx.x;
    if (blockIdx.x < 128) {
        short* wh_lds = (short*)smem;            // slot (kt*4+ct)*64+l, 8 shorts each
        short* wl_lds = (short*)(smem + 32768);
        int side = blockIdx.x >> 6;              // 0: q, 1: k
        const float* X = side ? Xk : Xq;
        const float* W = side ? Wk : Wq;
        // ---- stage W as bf16 hi/lo MFMA-B fragments (each element once) ----
        #pragma unroll
        for (int si = 0; si < 8; ++si) {
            int s = t * 8 + si;                  // 0..2047
            int l = s & 63, ct = (s >> 6) & 3, kt = s >> 8;
            int col = ct * 16 + (l & 15);
            int kb = kt * 32 + (l >> 4) * 8;
            short8 hi, lo;
            #pragma unroll
            for (int j = 0; j < 8; ++j) {
                float x = W[(kb + j) * Hh + col];
                short hs = f32_to_bf16(x);
                hi[j] = hs;
                lo[j] = f32_to_bf16(x - bf16_to_f32(hs));
            }
            *(short8*)(wh_lds + s * 8) = hi;
            *(short8*)(wl_lds + s * 8) = lo;
        }
        __syncthreads();
        // ---- per-wave 16x64 output tile, K=256 ----
        int wave = t >> 6, l = t & 63;
        int r0 = ((blockIdx.x & 63) * 4 + wave) * 16;   // row tile within side
        const float* xrow = X + (size_t)(r0 + (l & 15)) * Dd + (l >> 4) * 8;
        short8 ah[8], al[8];
        #pragma unroll
        for (int kt = 0; kt < 8; ++kt) {
            floatx4 a = *(const floatx4*)(xrow + kt * 32);
            floatx4 b = *(const floatx4*)(xrow + kt * 32 + 4);
            #pragma unroll
            for (int j = 0; j < 4; ++j) {
                short hs = f32_to_bf16(a[j]);
                ah[kt][j] = hs;
                al[kt][j] = f32_to_bf16(a[j] - bf16_to_f32(hs));
                short hs2 = f32_to_bf16(b[j]);
                ah[kt][j + 4] = hs2;
                al[kt][j + 4] = f32_to_bf16(b[j] - bf16_to_f32(hs2));
            }
        }
        floatx4 acc[4];
        #pragma unroll
        for (int ct = 0; ct < 4; ++ct) acc[ct] = (floatx4){0.f, 0.f, 0.f, 0.f};
        #pragma unroll
        for (int kt = 0; kt < 8; ++kt) {
            #pragma unroll
            for (int ct = 0; ct < 4; ++ct) {
                short8 wh = *(const short8*)(wh_lds + ((kt * 4 + ct) * 64 + l) * 8);
                short8 wl = *(const short8*)(wl_lds + ((kt * 4 + ct) * 64 + l) * 8);
                acc[ct] = __builtin_amdgcn_mfma_f32_16x16x32_bf16(ah[kt], wh, acc[ct], 0, 0, 0);
                acc[ct] = __builtin_amdgcn_mfma_f32_16x16x32_bf16(al[kt], wh, acc[ct], 0, 0, 0);
                acc[ct] = __builtin_amdgcn_mfma_f32_16x16x32_bf16(ah[kt], wl, acc[ct], 0, 0, 0);
            }
        }
        // ---- epilogue: exp-fold and store ----
        #pragma unroll
        for (int ct = 0; ct < 4; ++ct) {
            #pragma unroll
            for (int i = 0; i < 4; ++i) {
                float e = __expf(2.f * acc[ct][i]);
                int row = r0 + (l >> 4) * 4 + i;
                int h = ct * 16 + (l & 15);
                if (!side) {
                    Eq[(size_t)row * Hh + h] = e;      // coalesced per 16-lane group
                } else {
                    int b = row >> 10, k = row & 1023;
                    Ekt[((size_t)b * Hh + h) * Kn + k] = e;  // h-scatter, lines merge over i
                }
            }
        }
    } else {
        float* tile = (float*)smem;
        int blk = blockIdx.x - 128;
        int b = blk >> 5;
        int kt = blk & 31;
        const float* Vg = V + (b * Kn + kt * 32) * Dv;
        for (int i = 0; i < 8; ++i) {
            int k = i * 4 + (t >> 6);
            int n4 = (t & 63) * 4;
            float4 v = *(const float4*)(Vg + k * Dv + n4);
            tile[k * 261 + n4 + 0] = v.x;
            tile[k * 261 + n4 + 1] = v.y;
            tile[k * 261 + n4 + 2] = v.z;
            tile[k * 261 + n4 + 3] = v.w;
        }
        __syncthreads();
        int wave = t >> 6, l = t & 63;
        int n_in = l & 15, kc = l >> 4;
        for (int p = 0; p < 4; ++p) {
            int nt = wave * 4 + p;
            int n = nt * 16 + n_in;
            short8 hi, lo;
            #pragma unroll
            for (int j = 0; j < 8; ++j) {
                float x = tile[(kc * 8 + j) * 261 + n];
                short hs = f32_to_bf16(x);
                hi[j] = hs;
                lo[j] = f32_to_bf16(x - bf16_to_f32(hs));
            }
            size_t base = (((size_t)(b * 32 + kt) * 16 + nt) * 512) + (size_t)l * 8;
            *(short8*)(Vhi + base) = hi;
            *(short8*)(Vlo + base) = lo;
        }
    }
}

// score(q,k) = W_sum - 2*sum_h w_h/(Eq_h*Ek_h+1); W_sum cancels in softmax.
// R15 attn verbatim (last-good): 4-way rcp grouping, compiler-scheduled
// scalar fp32 (pk builtins scalarize; forced pk asm NaN'd — hazard-unsafe).
// Bounded scores -> no max-subtraction; p = exp(-2s) fused into score phase.
__global__ __launch_bounds__(1024, 4) void attn_kernel(const float* __restrict__ Eq,
                                                       const float* __restrict__ Ekt,
                                                       const short* __restrict__ Vhi,
                                                       const short* __restrict__ Vlo,
                                                       const float* __restrict__ wv,
                                                       float* __restrict__ out) {
    __shared__ __align__(16) unsigned sc[TQ * 1028];   // 65.8 KB: P hi/lo shorts
    __shared__ float wsum[16 * TQ];
    __shared__ float rinv_s[TQ];

    int tid = threadIdx.x;
    int blk = blockIdx.x;
    // XCD swizzle: blk%8 = XCD; batch b pinned to XCDs {2b,2b+1}.
    int b = (blk & 7) >> 1;
    int tile = (blk >> 3) * 2 + (blk & 1);   // 0..63, bijective per batch
    int qbase = tile * TQ;

    // ---- score phase: thread owns k = tid; q-pairs packed as float2 ----
    const float* kb = Ekt + (size_t)b * Hh * Kn;
    const float* qp = Eq + (size_t)(b * Qn + qbase) * Hh;
    const float4* wv4 = (const float4*)wv;
    floatx2 s2[TQ / 2];
    #pragma unroll
    for (int i = 0; i < TQ / 2; ++i) { s2[i].x = 0.f; s2[i].y = 0.f; }

    float e0 = kb[0 * Kn + tid];
    float e1 = kb[1 * Kn + tid];
    float e2 = kb[2 * Kn + tid];
    float e3 = kb[3 * Kn + tid];
    floatx2 one2 = mk2(1.f, 1.f);
    for (int h4 = 0; h4 < Hh / 4; ++h4) {
        float n0, n1, n2, n3;
        if (h4 < Hh / 4 - 1) {                 // prefetch next iteration
            const float* kn = kb + (h4 + 1) * 4 * Kn;
            n0 = kn[0 * Kn + tid];
            n1 = kn[1 * Kn + tid];
            n2 = kn[2 * Kn + tid];
            n3 = kn[3 * Kn + tid];
        }
        float4 w4 = wv4[h4];                            // uniform -> s_load
        floatx2 e0s = mk2(e0, e0), e1s = mk2(e1, e1);
        floatx2 e2s = mk2(e2, e2), e3s = mk2(e3, e3);
        floatx2 wx = mk2(w4.x, w4.x), wy = mk2(w4.y, w4.y);
        floatx2 wz = mk2(w4.z, w4.z), ww = mk2(w4.w, w4.w);
        #pragma unroll
        for (int qq = 0; qq < TQ; qq += 2) {
            float4 qva = *(const float4*)(qp + qq * Hh + h4 * 4);        // s_load
            float4 qvb = *(const float4*)(qp + (qq + 1) * Hh + h4 * 4);  // s_load
            floatx2 A = fma2(mk2(qva.x, qvb.x), e0s, one2);
            floatx2 B = fma2(mk2(qva.y, qvb.y), e1s, one2);
            floatx2 C = fma2(mk2(qva.z, qvb.z), e2s, one2);
            floatx2 D = fma2(mk2(qva.w, qvb.w), e3s, one2);
            floatx2 AB = A * B;
            floatx2 CD = C * D;
            floatx2 ABCD = AB * CD;
            floatx2 NAB = fma2(wx, B, wy * A);
            floatx2 NCD = fma2(wz, D, ww * C);
            floatx2 NUM = fma2(NCD, AB, NAB * CD);
            floatx2 R = mk2(__builtin_amdgcn_rcpf(ABCD.x),
                            __builtin_amdgcn_rcpf(ABCD.y));
            s2[qq >> 1] = fma2(NUM, R, s2[qq >> 1]);
        }
        e0 = n0; e1 = n1; e2 = n2; e3 = n3;
    }

    // p = exp(-2s); write bf16 hi/lo b16; per-q wave partials.
    unsigned short* sp = (unsigned short*)sc;
    float part[TQ];
    #pragma unroll
    for (int q = 0; q < TQ; ++q) {
        float sq = (q & 1) ? s2[q >> 1].y : s2[q >> 1].x;
        float p = __expf(-2.f * sq);
        part[q] = p;
        short hs = f32_to_bf16(p);
        sp[q * 2056 + tid] = (unsigned short)hs;
        sp[q * 2056 + 1024 + tid] = (unsigned short)f32_to_bf16(p - bf16_to_f32(hs));
    }

    int wave = tid >> 6, lane = tid & 63;
    #pragma unroll
    for (int q = 0; q < TQ; ++q) {
        #pragma unroll
        for (int off = 32; off >= 1; off >>= 1)
            part[q] += __shfl_xor(part[q], off, 64);
    }
    if (lane == 0) {
        #pragma unroll
        for (int q = 0; q < TQ; ++q) wsum[wave * TQ + q] = part[q];
    }
    __syncthreads();

    {   // wave w finalizes row q=w: sum 16 per-wave partials
        float v = (lane < 16) ? wsum[lane * TQ + wave] : 0.f;
        v += __shfl_xor(v, 8, 64);
        v += __shfl_xor(v, 4, 64);
        v += __shfl_xor(v, 2, 64);
        v += __shfl_xor(v, 1, 64);
        if (lane == 0) rinv_s[wave] = 1.f / v;
    }
    __syncthreads();

    // ---- AV via MFMA: wave owns ntile = wave; all 16 q-cols live ----
    int qf = lane & 15, kc = lane >> 4;
    floatx4 acc = {0.f, 0.f, 0.f, 0.f};
    const char* scb = (const char*)sc;
    for (int kt = 0; kt < 32; ++kt) {
        short8 bhi = *(const short8*)(scb + qf * 4112 + kt * 64 + kc * 16);
        short8 blo = *(const short8*)(scb + qf * 4112 + 2048 + kt * 64 + kc * 16);
        size_t base = (((size_t)(b * 32 + kt) * 16 + wave) * 512) + (size_t)lane * 8;
        short8 ah = *(const short8*)(Vhi + base);
        short8 al = *(const short8*)(Vlo + base);
        acc = __builtin_amdgcn_mfma_f32_16x16x32_bf16(ah, bhi, acc, 0, 0, 0);
        acc = __builtin_amdgcn_mfma_f32_16x16x32_bf16(al, bhi, acc, 0, 0, 0);
        acc = __builtin_amdgcn_mfma_f32_16x16x32_bf16(ah, blo, acc, 0, 0, 0);
    }
    {
        float r = rinv_s[qf];
        float* ob = out + ((size_t)(b * Qn + qbase + qf)) * Dv + wave * 16 + kc * 4;
        float4 o = { acc[0] * r, acc[1] * r, acc[2] * r, acc[3] * r };
        *(float4*)ob = o;
    }
}

extern "C" void kernel_launch(void* const* d_in, const int* in_sizes, int n_in,
                              void* d_out, int out_size, void* d_ws, size_t ws_size,
                              hipStream_t stream) {
    const float* queries = (const float*)d_in[0];
    const float* keys    = (const float*)d_in[1];
    const float* values  = (const float*)d_in[2];
    const float* W_q     = (const float*)d_in[3];
    const float* W_k     = (const float*)d_in[4];
    const float* w_v     = (const float*)d_in[5];
    float* out = (float*)d_out;

    float* Eq  = (float*)d_ws;                 // [B*Q, H]      1 MB
    float* Ekt = Eq + Bn * Qn * Hh;            // [B, H, K]     1 MB
    short* Vhi = (short*)(Ekt + Bn * Kn * Hh); // frag-order    2 MB
    short* Vlo = Vhi + (size_t)Bn * Kn * Dv;   // frag-order    2 MB

    prep_kernel<<<256, 256, 0, stream>>>(queries, W_q, keys, W_k, values,
                                         Eq, Ekt, Vhi, Vlo);
    attn_kernel<<<Bn * (Qn / TQ), 1024, 0, stream>>>(Eq, Ekt, Vhi, Vlo, w_v, out);
}

// Round 2
// 114.499 us; speedup vs baseline: 1.1006x; 1.0072x over previous
//
#include <hip/hip_runtime.h>

#define Bn 4
#define Qn 1024
#define Kn 1024
#define Dd 256
#define Hh 64
#define Dv 256
#define TQ 8

typedef __attribute__((ext_vector_type(8))) short short8;
typedef __attribute__((ext_vector_type(4))) float floatx4;
typedef __attribute__((ext_vector_type(2))) float floatx2;

__device__ __forceinline__ floatx2 fma2(floatx2 a, floatx2 b, floatx2 c) {
    return __builtin_elementwise_fma(a, b, c);
}
__device__ __forceinline__ floatx2 mk2(float x, float y) {
    floatx2 r; r.x = x; r.y = y; return r;
}

__device__ __forceinline__ short f32_to_bf16(float x) {
    unsigned u = __float_as_uint(x);
    unsigned r = u + 0x7fffu + ((u >> 16) & 1u);   // RNE
    return (short)(r >> 16);
}
__device__ __forceinline__ float bf16_to_f32(short h) {
    return __uint_as_float(((unsigned)(unsigned short)h) << 16);
}

// Fused prep v5: MFMA projections with coalesced W staging + float4 Ekt.
// R19 theory: v4's ~30us came from address divergence at 1 wave/SIMD:
//  (a) W staging slot s=t*8+si scattered each load instr over 64 lines;
//      s=si*256+t makes kt=si, ct=wave, lane=l -> 4 contiguous lines/instr,
//      SAME LDS frag layout (slot = kt*256+ct*64+l).
//  (b) Ekt epilogue wrote 16 scalar dwords/lane to rows 4KB apart (4B line
//      touches). C-frag reg i -> row kc*4+i = consecutive k, so one aligned
//      float4 per ct tiles exactly 16 full 64B lines per instr.
//  blocks 0..127  : projections (blk>>6 = side; 64 rows/block, 16/wave)
//  blocks 128..255: V -> split-bf16 MFMA-A-fragment swizzle (unchanged)
__global__ __launch_bounds__(256) void prep_kernel(const float* __restrict__ Xq,
                                                   const float* __restrict__ Wq,
                                                   const float* __restrict__ Xk,
                                                   const float* __restrict__ Wk,
                                                   const float* __restrict__ V,
                                                   float* __restrict__ Eq,
                                                   float* __restrict__ Ekt,
                                                   short* __restrict__ Vhi,
                                                   short* __restrict__ Vlo) {
    __shared__ __align__(16) char smem[65536];   // proj: W frags hi/lo (64KB); V: tile (33.4KB)
    int t = threadIdx.x;
    if (blockIdx.x < 128) {
        short* wh_lds = (short*)smem;            // slot (kt*4+ct)*64+l, 8 shorts each
        short* wl_lds = (short*)(smem + 32768);
        int side = blockIdx.x >> 6;              // 0: q, 1: k
        const float* X = side ? Xk : Xq;
        const float* W = side ? Wk : Wq;
        int wave = t >> 6, l = t & 63;
        // ---- stage W as bf16 hi/lo MFMA-B fragments, coalesced (4 lines/instr) ----
        #pragma unroll
        for (int si = 0; si < 8; ++si) {
            int s = si * 256 + t;                // kt=si, ct=wave, lane=l
            int col = wave * 16 + (l & 15);
            int kb = si * 32 + (l >> 4) * 8;
            short8 hi, lo;
            #pragma unroll
            for (int j = 0; j < 8; ++j) {
                float x = W[(kb + j) * Hh + col];
                short hs = f32_to_bf16(x);
                hi[j] = hs;
                lo[j] = f32_to_bf16(x - bf16_to_f32(hs));
            }
            *(short8*)(wh_lds + s * 8) = hi;
            *(short8*)(wl_lds + s * 8) = lo;
        }
        __syncthreads();
        // ---- per-wave 16x64 output tile, K=256 ----
        int r0 = ((blockIdx.x & 63) * 4 + wave) * 16;   // row tile within side
        const float* xrow = X + (size_t)(r0 + (l & 15)) * Dd + (l >> 4) * 8;
        short8 ah[8], al[8];
        #pragma unroll
        for (int kt = 0; kt < 8; ++kt) {
            floatx4 a = *(const floatx4*)(xrow + kt * 32);
            floatx4 b = *(const floatx4*)(xrow + kt * 32 + 4);
            #pragma unroll
            for (int j = 0; j < 4; ++j) {
                short hs = f32_to_bf16(a[j]);
                ah[kt][j] = hs;
                al[kt][j] = f32_to_bf16(a[j] - bf16_to_f32(hs));
                short hs2 = f32_to_bf16(b[j]);
                ah[kt][j + 4] = hs2;
                al[kt][j + 4] = f32_to_bf16(b[j] - bf16_to_f32(hs2));
            }
        }
        floatx4 acc[4];
        #pragma unroll
        for (int ct = 0; ct < 4; ++ct) acc[ct] = (floatx4){0.f, 0.f, 0.f, 0.f};
        #pragma unroll
        for (int kt = 0; kt < 8; ++kt) {
            #pragma unroll
            for (int ct = 0; ct < 4; ++ct) {
                short8 wh = *(const short8*)(wh_lds + ((kt * 4 + ct) * 64 + l) * 8);
                short8 wl = *(const short8*)(wl_lds + ((kt * 4 + ct) * 64 + l) * 8);
                acc[ct] = __builtin_amdgcn_mfma_f32_16x16x32_bf16(ah[kt], wh, acc[ct], 0, 0, 0);
                acc[ct] = __builtin_amdgcn_mfma_f32_16x16x32_bf16(al[kt], wh, acc[ct], 0, 0, 0);
                acc[ct] = __builtin_amdgcn_mfma_f32_16x16x32_bf16(ah[kt], wl, acc[ct], 0, 0, 0);
            }
        }
        // ---- epilogue: exp-fold and store ----
        #pragma unroll
        for (int ct = 0; ct < 4; ++ct) {
            int h = ct * 16 + (l & 15);
            float e0 = __expf(2.f * acc[ct][0]);
            float e1 = __expf(2.f * acc[ct][1]);
            float e2 = __expf(2.f * acc[ct][2]);
            float e3 = __expf(2.f * acc[ct][3]);
            int row0g = r0 + (l >> 4) * 4;       // row of reg i=0; i-consecutive = k-consecutive
            if (!side) {
                Eq[(size_t)(row0g + 0) * Hh + h] = e0;   // 16 consecutive h per instr
                Eq[(size_t)(row0g + 1) * Hh + h] = e1;
                Eq[(size_t)(row0g + 2) * Hh + h] = e2;
                Eq[(size_t)(row0g + 3) * Hh + h] = e3;
            } else {
                int b = row0g >> 10, k0 = row0g & 1023;  // never straddles (r0%16==0)
                float4 o = { e0, e1, e2, e3 };
                *(float4*)(Ekt + ((size_t)(b * Hh + h)) * Kn + k0) = o;  // 16 full lines/instr
            }
        }
    } else {
        float* tile = (float*)smem;
        int blk = blockIdx.x - 128;
        int b = blk >> 5;
        int kt = blk & 31;
        const float* Vg = V + (b * Kn + kt * 32) * Dv;
        for (int i = 0; i < 8; ++i) {
            int k = i * 4 + (t >> 6);
            int n4 = (t & 63) * 4;
            float4 v = *(const float4*)(Vg + k * Dv + n4);
            tile[k * 261 + n4 + 0] = v.x;
            tile[k * 261 + n4 + 1] = v.y;
            tile[k * 261 + n4 + 2] = v.z;
            tile[k * 261 + n4 + 3] = v.w;
        }
        __syncthreads();
        int wave = t >> 6, l = t & 63;
        int n_in = l & 15, kc = l >> 4;
        for (int p = 0; p < 4; ++p) {
            int nt = wave * 4 + p;
            int n = nt * 16 + n_in;
            short8 hi, lo;
            #pragma unroll
            for (int j = 0; j < 8; ++j) {
                float x = tile[(kc * 8 + j) * 261 + n];
                short hs = f32_to_bf16(x);
                hi[j] = hs;
                lo[j] = f32_to_bf16(x - bf16_to_f32(hs));
            }
            size_t base = (((size_t)(b * 32 + kt) * 16 + nt) * 512) + (size_t)l * 8;
            *(short8*)(Vhi + base) = hi;
            *(short8*)(Vlo + base) = lo;
        }
    }
}

// score(q,k) = W_sum - 2*sum_h w_h/(Eq_h*Ek_h+1); W_sum cancels in softmax.
// R19: TQ 16->8, grid 512, LDS 33.4KB -> 2 blocks/CU (32 waves, was 1 block).
// One block's score VALU hides the other's barriers/loads. AV B-frag cols
// 8..15 alias q&7 (computed, not stored). Math identical to R15 attn.
__global__ __launch_bounds__(1024, 8) void attn_kernel(const float* __restrict__ Eq,
                                                       const float* __restrict__ Ekt,
                                                       const short* __restrict__ Vhi,
                                                       const short* __restrict__ Vlo,
                                                       const float* __restrict__ wv,
                                                       float* __restrict__ out) {
    __shared__ __align__(16) unsigned sc[TQ * 1028];   // 32.9 KB: P hi/lo shorts
    __shared__ float wsum[16 * TQ];
    __shared__ float rinv_s[TQ];

    int tid = threadIdx.x;
    int blk = blockIdx.x;
    // XCD swizzle: blk%8 = XCD; batch b pinned to XCDs {2b,2b+1}.
    int b = (blk & 7) >> 1;
    int tile = (blk >> 3) * 2 + (blk & 1);   // 0..127, bijective per batch
    int qbase = tile * TQ;

    // ---- score phase: thread owns k = tid; q-pairs packed as float2 ----
    const float* kb = Ekt + (size_t)b * Hh * Kn;
    const float* qp = Eq + (size_t)(b * Qn + qbase) * Hh;
    const float4* wv4 = (const float4*)wv;
    floatx2 s2[TQ / 2];
    #pragma unroll
    for (int i = 0; i < TQ / 2; ++i) { s2[i].x = 0.f; s2[i].y = 0.f; }

    float e0 = kb[0 * Kn + tid];
    float e1 = kb[1 * Kn + tid];
    float e2 = kb[2 * Kn + tid];
    float e3 = kb[3 * Kn + tid];
    floatx2 one2 = mk2(1.f, 1.f);
    for (int h4 = 0; h4 < Hh / 4; ++h4) {
        float n0, n1, n2, n3;
        if (h4 < Hh / 4 - 1) {                 // prefetch next iteration
            const float* kn = kb + (h4 + 1) * 4 * Kn;
            n0 = kn[0 * Kn + tid];
            n1 = kn[1 * Kn + tid];
            n2 = kn[2 * Kn + tid];
            n3 = kn[3 * Kn + tid];
        }
        float4 w4 = wv4[h4];                            // uniform -> s_load
        floatx2 e0s = mk2(e0, e0), e1s = mk2(e1, e1);
        floatx2 e2s = mk2(e2, e2), e3s = mk2(e3, e3);
        floatx2 wx = mk2(w4.x, w4.x), wy = mk2(w4.y, w4.y);
        floatx2 wz = mk2(w4.z, w4.z), ww = mk2(w4.w, w4.w);
        #pragma unroll
        for (int qq = 0; qq < TQ; qq += 2) {
            float4 qva = *(const float4*)(qp + qq * Hh + h4 * 4);        // s_load
            float4 qvb = *(const float4*)(qp + (qq + 1) * Hh + h4 * 4);  // s_load
            floatx2 A = fma2(mk2(qva.x, qvb.x), e0s, one2);
            floatx2 B = fma2(mk2(qva.y, qvb.y), e1s, one2);
            floatx2 C = fma2(mk2(qva.z, qvb.z), e2s, one2);
            floatx2 D = fma2(mk2(qva.w, qvb.w), e3s, one2);
            floatx2 AB = A * B;
            floatx2 CD = C * D;
            floatx2 ABCD = AB * CD;
            floatx2 NAB = fma2(wx, B, wy * A);
            floatx2 NCD = fma2(wz, D, ww * C);
            floatx2 NUM = fma2(NCD, AB, NAB * CD);
            floatx2 R = mk2(__builtin_amdgcn_rcpf(ABCD.x),
                            __builtin_amdgcn_rcpf(ABCD.y));
            s2[qq >> 1] = fma2(NUM, R, s2[qq >> 1]);
        }
        e0 = n0; e1 = n1; e2 = n2; e3 = n3;
    }

    // p = exp(-2s); write bf16 hi/lo b16; per-q wave partials.
    unsigned short* sp = (unsigned short*)sc;
    float part[TQ];
    #pragma unroll
    for (int q = 0; q < TQ; ++q) {
        float sq = (q & 1) ? s2[q >> 1].y : s2[q >> 1].x;
        float p = __expf(-2.f * sq);
        part[q] = p;
        short hs = f32_to_bf16(p);
        sp[q * 2056 + tid] = (unsigned short)hs;
        sp[q * 2056 + 1024 + tid] = (unsigned short)f32_to_bf16(p - bf16_to_f32(hs));
    }

    int wave = tid >> 6, lane = tid & 63;
    #pragma unroll
    for (int q = 0; q < TQ; ++q) {
        #pragma unroll
        for (int off = 32; off >= 1; off >>= 1)
            part[q] += __shfl_xor(part[q], off, 64);
    }
    if (lane == 0) {
        #pragma unroll
        for (int q = 0; q < TQ; ++q) wsum[wave * TQ + q] = part[q];
    }
    __syncthreads();

    if (wave < TQ) {   // wave w finalizes row q=w: sum 16 per-wave partials
        float v = (lane < 16) ? wsum[lane * TQ + wave] : 0.f;
        v += __shfl_xor(v, 8, 64);
        v += __shfl_xor(v, 4, 64);
        v += __shfl_xor(v, 2, 64);
        v += __shfl_xor(v, 1, 64);
        if (lane == 0) rinv_s[wave] = 1.f / v;
    }
    __syncthreads();

    // ---- AV via MFMA: wave owns ntile = wave; B cols 8..15 alias q&7 ----
    int qf = lane & 15, kc = lane >> 4;
    int qd = qf & (TQ - 1);
    floatx4 acc = {0.f, 0.f, 0.f, 0.f};
    const char* scb = (const char*)sc;
    for (int kt = 0; kt < 32; ++kt) {
        short8 bhi = *(const short8*)(scb + qd * 4112 + kt * 64 + kc * 16);
        short8 blo = *(const short8*)(scb + qd * 4112 + 2048 + kt * 64 + kc * 16);
        size_t base = (((size_t)(b * 32 + kt) * 16 + wave) * 512) + (size_t)lane * 8;
        short8 ah = *(const short8*)(Vhi + base);
        short8 al = *(const short8*)(Vlo + base);
        acc = __builtin_amdgcn_mfma_f32_16x16x32_bf16(ah, bhi, acc, 0, 0, 0);
        acc = __builtin_amdgcn_mfma_f32_16x16x32_bf16(al, bhi, acc, 0, 0, 0);
        acc = __builtin_amdgcn_mfma_f32_16x16x32_bf16(ah, blo, acc, 0, 0, 0);
    }
    if (qf < TQ) {
        float r = rinv_s[qd];
        float* ob = out + ((size_t)(b * Qn + qbase + qf)) * Dv + wave * 16 + kc * 4;
        float4 o = { acc[0] * r, acc[1] * r, acc[2] * r, acc[3] * r };
        *(float4*)ob = o;
    }
}

extern "C" void kernel_launch(void* const* d_in, const int* in_sizes, int n_in,
                              void* d_out, int out_size, void* d_ws, size_t ws_size,
                              hipStream_t stream) {
    const float* queries = (const float*)d_in[0];
    const float* keys    = (const float*)d_in[1];
    const float* values  = (const float*)d_in[2];
    const float* W_q     = (const float*)d_in[3];
    const float* W_k     = (const float*)d_in[4];
    const float* w_v     = (const float*)d_in[5];
    float* out = (float*)d_out;

    float* Eq  = (float*)d_ws;                 // [B*Q, H]      1 MB
    float* Ekt = Eq + Bn * Qn * Hh;            // [B, H, K]     1 MB
    short* Vhi = (short*)(Ekt + Bn * Kn * Hh); // frag-order    2 MB
    short* Vlo = Vhi + (size_t)Bn * Kn * Dv;   // frag-order    2 MB

    prep_kernel<<<256, 256, 0, stream>>>(queries, W_q, keys, W_k, values,
                                         Eq, Ekt, Vhi, Vlo);
    attn_kernel<<<Bn * (Qn / TQ), 1024, 0, stream>>>(Eq, Ekt, Vhi, Vlo, w_v, out);
}

// Round 3
// 110.840 us; speedup vs baseline: 1.1369x; 1.0330x over previous
//
#include <hip/hip_runtime.h>

#define Bn 4
#define Qn 1024
#define Kn 1024
#define Dd 256
#define Hh 64
#define Dv 256
#define TQ 8

typedef __attribute__((ext_vector_type(8))) short short8;
typedef __attribute__((ext_vector_type(8))) _Float16 half8;
typedef __attribute__((ext_vector_type(4))) float floatx4;
typedef __attribute__((ext_vector_type(2))) float floatx2;

__device__ __forceinline__ floatx2 fma2(floatx2 a, floatx2 b, floatx2 c) {
    return __builtin_elementwise_fma(a, b, c);
}
__device__ __forceinline__ floatx2 mk2(float x, float y) {
    floatx2 r; r.x = x; r.y = y; return r;
}

__device__ __forceinline__ short f32_to_bf16(float x) {
    unsigned u = __float_as_uint(x);
    unsigned r = u + 0x7fffu + ((u >> 16) & 1u);   // RNE
    return (short)(r >> 16);
}
__device__ __forceinline__ float bf16_to_f32(short h) {
    return __uint_as_float(((unsigned)(unsigned short)h) << 16);
}

// Fused prep v6: MFMA projections (bf16-split, unchanged math) + fp16 V.
// R20: (a) X-tile loads hoisted BEFORE W staging: at 1 wave/SIMD the old
// order exposed two serial HBM latencies; now X is in flight under the
// W stage+cvt phase. (b) V-swizzle emits a SINGLE fp16 array (R20 switched
// the AV path to fp16; V traffic in attn drops 4x vs split-bf16@TQ8).
//  blocks 0..127  : projections (blk>>6 = side; 64 rows/block, 16/wave)
//  blocks 128..255: V -> fp16 MFMA-A-fragment swizzle
__global__ __launch_bounds__(256) void prep_kernel(const float* __restrict__ Xq,
                                                   const float* __restrict__ Wq,
                                                   const float* __restrict__ Xk,
                                                   const float* __restrict__ Wk,
                                                   const float* __restrict__ V,
                                                   float* __restrict__ Eq,
                                                   float* __restrict__ Ekt,
                                                   _Float16* __restrict__ Vh) {
    __shared__ __align__(16) char smem[65536];   // proj: W frags hi/lo (64KB); V: tile (33.4KB)
    int t = threadIdx.x;
    if (blockIdx.x < 128) {
        short* wh_lds = (short*)smem;            // slot (kt*4+ct)*64+l, 8 shorts each
        short* wl_lds = (short*)(smem + 32768);
        int side = blockIdx.x >> 6;              // 0: q, 1: k
        const float* X = side ? Xk : Xq;
        const float* W = side ? Wk : Wq;
        int wave = t >> 6, l = t & 63;
        // ---- issue X loads first (in flight under W staging) ----
        int r0 = ((blockIdx.x & 63) * 4 + wave) * 16;   // row tile within side
        const float* xrow = X + (size_t)(r0 + (l & 15)) * Dd + (l >> 4) * 8;
        floatx4 xa[8], xb[8];
        #pragma unroll
        for (int kt = 0; kt < 8; ++kt) {
            xa[kt] = *(const floatx4*)(xrow + kt * 32);
            xb[kt] = *(const floatx4*)(xrow + kt * 32 + 4);
        }
        // ---- stage W as bf16 hi/lo MFMA-B fragments, coalesced (4 lines/instr) ----
        #pragma unroll
        for (int si = 0; si < 8; ++si) {
            int s = si * 256 + t;                // kt=si, ct=wave, lane=l
            int col = wave * 16 + (l & 15);
            int kb = si * 32 + (l >> 4) * 8;
            short8 hi, lo;
            #pragma unroll
            for (int j = 0; j < 8; ++j) {
                float x = W[(kb + j) * Hh + col];
                short hs = f32_to_bf16(x);
                hi[j] = hs;
                lo[j] = f32_to_bf16(x - bf16_to_f32(hs));
            }
            *(short8*)(wh_lds + s * 8) = hi;
            *(short8*)(wl_lds + s * 8) = lo;
        }
        __syncthreads();
        // ---- cvt X to bf16 hi/lo fragments ----
        short8 ah[8], al[8];
        #pragma unroll
        for (int kt = 0; kt < 8; ++kt) {
            #pragma unroll
            for (int j = 0; j < 4; ++j) {
                short hs = f32_to_bf16(xa[kt][j]);
                ah[kt][j] = hs;
                al[kt][j] = f32_to_bf16(xa[kt][j] - bf16_to_f32(hs));
                short hs2 = f32_to_bf16(xb[kt][j]);
                ah[kt][j + 4] = hs2;
                al[kt][j + 4] = f32_to_bf16(xb[kt][j] - bf16_to_f32(hs2));
            }
        }
        floatx4 acc[4];
        #pragma unroll
        for (int ct = 0; ct < 4; ++ct) acc[ct] = (floatx4){0.f, 0.f, 0.f, 0.f};
        #pragma unroll
        for (int kt = 0; kt < 8; ++kt) {
            #pragma unroll
            for (int ct = 0; ct < 4; ++ct) {
                short8 wh = *(const short8*)(wh_lds + ((kt * 4 + ct) * 64 + l) * 8);
                short8 wl = *(const short8*)(wl_lds + ((kt * 4 + ct) * 64 + l) * 8);
                acc[ct] = __builtin_amdgcn_mfma_f32_16x16x32_bf16(ah[kt], wh, acc[ct], 0, 0, 0);
                acc[ct] = __builtin_amdgcn_mfma_f32_16x16x32_bf16(al[kt], wh, acc[ct], 0, 0, 0);
                acc[ct] = __builtin_amdgcn_mfma_f32_16x16x32_bf16(ah[kt], wl, acc[ct], 0, 0, 0);
            }
        }
        // ---- epilogue: exp-fold and store ----
        #pragma unroll
        for (int ct = 0; ct < 4; ++ct) {
            int h = ct * 16 + (l & 15);
            float e0 = __expf(2.f * acc[ct][0]);
            float e1 = __expf(2.f * acc[ct][1]);
            float e2 = __expf(2.f * acc[ct][2]);
            float e3 = __expf(2.f * acc[ct][3]);
            int row0g = r0 + (l >> 4) * 4;       // reg i -> consecutive rows
            if (!side) {
                Eq[(size_t)(row0g + 0) * Hh + h] = e0;
                Eq[(size_t)(row0g + 1) * Hh + h] = e1;
                Eq[(size_t)(row0g + 2) * Hh + h] = e2;
                Eq[(size_t)(row0g + 3) * Hh + h] = e3;
            } else {
                int b = row0g >> 10, k0 = row0g & 1023;
                float4 o = { e0, e1, e2, e3 };
                *(float4*)(Ekt + ((size_t)(b * Hh + h)) * Kn + k0) = o;  // 16 full lines/instr
            }
        }
    } else {
        float* tile = (float*)smem;
        int blk = blockIdx.x - 128;
        int b = blk >> 5;
        int kt = blk & 31;
        const float* Vg = V + (b * Kn + kt * 32) * Dv;
        for (int i = 0; i < 8; ++i) {
            int k = i * 4 + (t >> 6);
            int n4 = (t & 63) * 4;
            float4 v = *(const float4*)(Vg + k * Dv + n4);
            tile[k * 261 + n4 + 0] = v.x;
            tile[k * 261 + n4 + 1] = v.y;
            tile[k * 261 + n4 + 2] = v.z;
            tile[k * 261 + n4 + 3] = v.w;
        }
        __syncthreads();
        int wave = t >> 6, l = t & 63;
        int n_in = l & 15, kc = l >> 4;
        for (int p = 0; p < 4; ++p) {
            int nt = wave * 4 + p;
            int n = nt * 16 + n_in;
            half8 hi;
            #pragma unroll
            for (int j = 0; j < 8; ++j) {
                hi[j] = (_Float16)tile[(kc * 8 + j) * 261 + n];
            }
            size_t base = (((size_t)(b * 32 + kt) * 16 + nt) * 512) + (size_t)l * 8;
            *(half8*)(Vh + base) = hi;
        }
    }
}

// score(q,k) = W_sum - 2*sum_h w_h/(Eq_h*Ek_h+1); W_sum cancels in softmax.
// R20: AV path in fp16 — P split hi/lo fp16 in LDS (err ~2^-22), V single
// fp16 (err 2^-11 rel, cancels over K in the weighted avg). 2 MFMAs/kt,
// 1 global b128->b64-equivalent V load/kt. Score phase math unchanged
// (fp32, rcp-grouped). TQ=8, grid 512, 2 blocks/CU.
__global__ __launch_bounds__(1024, 8) void attn_kernel(const float* __restrict__ Eq,
                                                       const float* __restrict__ Ekt,
                                                       const _Float16* __restrict__ Vh,
                                                       const float* __restrict__ wv,
                                                       float* __restrict__ out) {
    __shared__ __align__(16) unsigned sc[TQ * 1028];   // 32.9 KB: P hi/lo fp16
    __shared__ float wsum[16 * TQ];
    __shared__ float rinv_s[TQ];

    int tid = threadIdx.x;
    int blk = blockIdx.x;
    // XCD swizzle: blk%8 = XCD; batch b pinned to XCDs {2b,2b+1}.
    int b = (blk & 7) >> 1;
    int tile = (blk >> 3) * 2 + (blk & 1);   // 0..127, bijective per batch
    int qbase = tile * TQ;

    // ---- score phase: thread owns k = tid; q-pairs packed as float2 ----
    const float* kb = Ekt + (size_t)b * Hh * Kn;
    const float* qp = Eq + (size_t)(b * Qn + qbase) * Hh;
    const float4* wv4 = (const float4*)wv;
    floatx2 s2[TQ / 2];
    #pragma unroll
    for (int i = 0; i < TQ / 2; ++i) { s2[i].x = 0.f; s2[i].y = 0.f; }

    float e0 = kb[0 * Kn + tid];
    float e1 = kb[1 * Kn + tid];
    float e2 = kb[2 * Kn + tid];
    float e3 = kb[3 * Kn + tid];
    floatx2 one2 = mk2(1.f, 1.f);
    for (int h4 = 0; h4 < Hh / 4; ++h4) {
        float n0, n1, n2, n3;
        if (h4 < Hh / 4 - 1) {                 // prefetch next iteration
            const float* kn = kb + (h4 + 1) * 4 * Kn;
            n0 = kn[0 * Kn + tid];
            n1 = kn[1 * Kn + tid];
            n2 = kn[2 * Kn + tid];
            n3 = kn[3 * Kn + tid];
        }
        float4 w4 = wv4[h4];                            // uniform -> s_load
        floatx2 e0s = mk2(e0, e0), e1s = mk2(e1, e1);
        floatx2 e2s = mk2(e2, e2), e3s = mk2(e3, e3);
        floatx2 wx = mk2(w4.x, w4.x), wy = mk2(w4.y, w4.y);
        floatx2 wz = mk2(w4.z, w4.z), ww = mk2(w4.w, w4.w);
        #pragma unroll
        for (int qq = 0; qq < TQ; qq += 2) {
            float4 qva = *(const float4*)(qp + qq * Hh + h4 * 4);        // s_load
            float4 qvb = *(const float4*)(qp + (qq + 1) * Hh + h4 * 4);  // s_load
            floatx2 A = fma2(mk2(qva.x, qvb.x), e0s, one2);
            floatx2 B = fma2(mk2(qva.y, qvb.y), e1s, one2);
            floatx2 C = fma2(mk2(qva.z, qvb.z), e2s, one2);
            floatx2 D = fma2(mk2(qva.w, qvb.w), e3s, one2);
            floatx2 AB = A * B;
            floatx2 CD = C * D;
            floatx2 ABCD = AB * CD;
            floatx2 NAB = fma2(wx, B, wy * A);
            floatx2 NCD = fma2(wz, D, ww * C);
            floatx2 NUM = fma2(NCD, AB, NAB * CD);
            floatx2 R = mk2(__builtin_amdgcn_rcpf(ABCD.x),
                            __builtin_amdgcn_rcpf(ABCD.y));
            s2[qq >> 1] = fma2(NUM, R, s2[qq >> 1]);
        }
        e0 = n0; e1 = n1; e2 = n2; e3 = n3;
    }

    // p = exp(-2s); write fp16 hi/lo; per-q wave partials (fp32 p).
    _Float16* sp = (_Float16*)sc;
    float part[TQ];
    #pragma unroll
    for (int q = 0; q < TQ; ++q) {
        float sq = (q & 1) ? s2[q >> 1].y : s2[q >> 1].x;
        float p = __expf(-2.f * sq);
        part[q] = p;
        _Float16 hs = (_Float16)p;
        sp[q * 2056 + tid] = hs;
        sp[q * 2056 + 1024 + tid] = (_Float16)(p - (float)hs);
    }

    int wave = tid >> 6, lane = tid & 63;
    #pragma unroll
    for (int q = 0; q < TQ; ++q) {
        #pragma unroll
        for (int off = 32; off >= 1; off >>= 1)
            part[q] += __shfl_xor(part[q], off, 64);
    }
    if (lane == 0) {
        #pragma unroll
        for (int q = 0; q < TQ; ++q) wsum[wave * TQ + q] = part[q];
    }
    __syncthreads();

    if (wave < TQ) {   // wave w finalizes row q=w: sum 16 per-wave partials
        float v = (lane < 16) ? wsum[lane * TQ + wave] : 0.f;
        v += __shfl_xor(v, 8, 64);
        v += __shfl_xor(v, 4, 64);
        v += __shfl_xor(v, 2, 64);
        v += __shfl_xor(v, 1, 64);
        if (lane == 0) rinv_s[wave] = 1.f / v;
    }
    __syncthreads();

    // ---- AV via fp16 MFMA: wave owns ntile = wave; B cols 8..15 alias q&7 ----
    int qf = lane & 15, kc = lane >> 4;
    int qd = qf & (TQ - 1);
    floatx4 acc = {0.f, 0.f, 0.f, 0.f};
    const char* scb = (const char*)sc;
    for (int kt = 0; kt < 32; ++kt) {
        half8 bhi = *(const half8*)(scb + qd * 4112 + kt * 64 + kc * 16);
        half8 blo = *(const half8*)(scb + qd * 4112 + 2048 + kt * 64 + kc * 16);
        size_t base = (((size_t)(b * 32 + kt) * 16 + wave) * 512) + (size_t)lane * 8;
        half8 ah = *(const half8*)(Vh + base);
        acc = __builtin_amdgcn_mfma_f32_16x16x32_f16(ah, bhi, acc, 0, 0, 0);
        acc = __builtin_amdgcn_mfma_f32_16x16x32_f16(ah, blo, acc, 0, 0, 0);
    }
    if (qf < TQ) {
        float r = rinv_s[qd];
        float* ob = out + ((size_t)(b * Qn + qbase + qf)) * Dv + wave * 16 + kc * 4;
        float4 o = { acc[0] * r, acc[1] * r, acc[2] * r, acc[3] * r };
        *(float4*)ob = o;
    }
}

extern "C" void kernel_launch(void* const* d_in, const int* in_sizes, int n_in,
                              void* d_out, int out_size, void* d_ws, size_t ws_size,
                              hipStream_t stream) {
    const float* queries = (const float*)d_in[0];
    const float* keys    = (const float*)d_in[1];
    const float* values  = (const float*)d_in[2];
    const float* W_q     = (const float*)d_in[3];
    const float* W_k     = (const float*)d_in[4];
    const float* w_v     = (const float*)d_in[5];
    float* out = (float*)d_out;

    float* Eq  = (float*)d_ws;                    // [B*Q, H]      1 MB
    float* Ekt = Eq + Bn * Qn * Hh;               // [B, H, K]     1 MB
    _Float16* Vh = (_Float16*)(Ekt + Bn * Kn * Hh); // frag-order  2 MB

    prep_kernel<<<256, 256, 0, stream>>>(queries, W_q, keys, W_k, values,
                                         Eq, Ekt, Vh);
    attn_kernel<<<Bn * (Qn / TQ), 1024, 0, stream>>>(Eq, Ekt, Vh, w_v, out);
}

// Round 4
// 110.181 us; speedup vs baseline: 1.1437x; 1.0060x over previous
//
#include <hip/hip_runtime.h>

#define Bn 4
#define Qn 1024
#define Kn 1024
#define Dd 256
#define Hh 64
#define Dv 256
#define TQ 8

typedef __attribute__((ext_vector_type(8))) short short8;
typedef __attribute__((ext_vector_type(8))) _Float16 half8;
typedef __attribute__((ext_vector_type(4))) float floatx4;
typedef __attribute__((ext_vector_type(2))) float floatx2;

__device__ __forceinline__ floatx2 fma2(floatx2 a, floatx2 b, floatx2 c) {
    return __builtin_elementwise_fma(a, b, c);
}
__device__ __forceinline__ floatx2 mk2(float x, float y) {
    floatx2 r; r.x = x; r.y = y; return r;
}

__device__ __forceinline__ short f32_to_bf16(float x) {
    unsigned u = __float_as_uint(x);
    unsigned r = u + 0x7fffu + ((u >> 16) & 1u);   // RNE
    return (short)(r >> 16);
}
__device__ __forceinline__ float bf16_to_f32(short h) {
    return __uint_as_float(((unsigned)(unsigned short)h) << 16);
}

// Fused prep v7: fully LDS-free / barrier-free. R21 theory: v6's ~25us was
// latency at 1 wave/SIMD + block barrier gating (staged-W __syncthreads).
// Nothing here needs LDS: W B-frags and V A-frags are per-lane gathers that
// are 4x64B-line coalesced per instruction and L2-hot. Decomposition:
//  blocks 0..511  : proj. side=blk>>8, row-tile=(blk&255)*16. Wave ct=w
//                   owns a 16x16 output tile: 16 b128 X loads + 64 scalar
//                   W loads (its 16-col slice), split-bf16, 24 MFMA,
//                   exp-fold epilogue. No sync -> waves run free.
//  blocks 512..639: V -> fp16 A-frag swizzle, direct gather (32 scalar
//                   loads, 4 lines/instr), 4 b128 stores. No sync.
// 640 blocks = 2.5 waves/SIMD of barrier-less latency overlap.
__global__ __launch_bounds__(256) void prep_kernel(const float* __restrict__ Xq,
                                                   const float* __restrict__ Wq,
                                                   const float* __restrict__ Xk,
                                                   const float* __restrict__ Wk,
                                                   const float* __restrict__ V,
                                                   float* __restrict__ Eq,
                                                   float* __restrict__ Ekt,
                                                   _Float16* __restrict__ Vh) {
    int t = threadIdx.x;
    int wave = t >> 6, l = t & 63;
    if (blockIdx.x < 512) {
        int side = blockIdx.x >> 8;              // 0: q, 1: k
        int r0 = (blockIdx.x & 255) * 16;        // row tile within side
        int ct = wave;                           // 16-col slice of H
        const float* X = side ? Xk : Xq;
        const float* W = side ? Wk : Wq;
        // ---- X loads (issued first, all in flight) ----
        const float* xrow = X + (size_t)(r0 + (l & 15)) * Dd + (l >> 4) * 8;
        floatx4 xa[8], xb[8];
        #pragma unroll
        for (int kt = 0; kt < 8; ++kt) {
            xa[kt] = *(const floatx4*)(xrow + kt * 32);
            xb[kt] = *(const floatx4*)(xrow + kt * 32 + 4);
        }
        // ---- W slice gather: 64 scalar loads, 4x64B lines per instr ----
        float wraw[8][8];
        #pragma unroll
        for (int kt = 0; kt < 8; ++kt) {
            const float* wp = W + (size_t)(kt * 32 + (l >> 4) * 8) * Hh + ct * 16 + (l & 15);
            #pragma unroll
            for (int j = 0; j < 8; ++j) wraw[kt][j] = wp[j * Hh];
        }
        // ---- split-bf16 fragments ----
        short8 ah[8], al[8], wh[8], wl[8];
        #pragma unroll
        for (int kt = 0; kt < 8; ++kt) {
            #pragma unroll
            for (int j = 0; j < 4; ++j) {
                short hs = f32_to_bf16(xa[kt][j]);
                ah[kt][j] = hs;
                al[kt][j] = f32_to_bf16(xa[kt][j] - bf16_to_f32(hs));
                short hs2 = f32_to_bf16(xb[kt][j]);
                ah[kt][j + 4] = hs2;
                al[kt][j + 4] = f32_to_bf16(xb[kt][j] - bf16_to_f32(hs2));
            }
            #pragma unroll
            for (int j = 0; j < 8; ++j) {
                short hs = f32_to_bf16(wraw[kt][j]);
                wh[kt][j] = hs;
                wl[kt][j] = f32_to_bf16(wraw[kt][j] - bf16_to_f32(hs));
            }
        }
        floatx4 acc = {0.f, 0.f, 0.f, 0.f};
        #pragma unroll
        for (int kt = 0; kt < 8; ++kt) {
            acc = __builtin_amdgcn_mfma_f32_16x16x32_bf16(ah[kt], wh[kt], acc, 0, 0, 0);
            acc = __builtin_amdgcn_mfma_f32_16x16x32_bf16(al[kt], wh[kt], acc, 0, 0, 0);
            acc = __builtin_amdgcn_mfma_f32_16x16x32_bf16(ah[kt], wl[kt], acc, 0, 0, 0);
        }
        // ---- epilogue: exp-fold and store ----
        int h = ct * 16 + (l & 15);
        float e0 = __expf(2.f * acc[0]);
        float e1 = __expf(2.f * acc[1]);
        float e2 = __expf(2.f * acc[2]);
        float e3 = __expf(2.f * acc[3]);
        int row0g = r0 + (l >> 4) * 4;           // reg i -> consecutive rows
        if (!side) {
            Eq[(size_t)(row0g + 0) * Hh + h] = e0;
            Eq[(size_t)(row0g + 1) * Hh + h] = e1;
            Eq[(size_t)(row0g + 2) * Hh + h] = e2;
            Eq[(size_t)(row0g + 3) * Hh + h] = e3;
        } else {
            int b = row0g >> 10, k0 = row0g & 1023;
            float4 o = { e0, e1, e2, e3 };
            *(float4*)(Ekt + ((size_t)(b * Hh + h)) * Kn + k0) = o;  // 16 full lines/instr
        }
    } else {
        int vblk = blockIdx.x - 512;
        int b = vblk >> 5;
        int kt = vblk & 31;
        const float* Vg = V + ((size_t)(b * Kn + kt * 32 + (l >> 4) * 8)) * Dv + (l & 15);
        #pragma unroll
        for (int p = 0; p < 4; ++p) {
            int nt = wave * 4 + p;
            const float* vp = Vg + nt * 16;
            half8 hv;
            #pragma unroll
            for (int j = 0; j < 8; ++j)
                hv[j] = (_Float16)vp[(size_t)j * Dv];
            size_t base = (((size_t)(b * 32 + kt) * 16 + nt) * 512) + (size_t)l * 8;
            *(half8*)(Vh + base) = hv;
        }
    }
}

// score(q,k) = W_sum - 2*sum_h w_h/(Eq_h*Ek_h+1); W_sum cancels in softmax.
// R21: (1) V prefetch — V loads are P-independent, so V(kt=0) issues right
// after the score phase (L2 latency hides under exp/pack/shuffle/barrier)
// and the AV loop prefetches vnext before each kt's MFMAs. (2) single
// barrier — rinv computed per-thread from the 16 wsum partials after the
// MFMA loop (broadcast LDS reads), removing the wave-specialized finalize
// and second __syncthreads. Score math unchanged (fp32, rcp-grouped).
__global__ __launch_bounds__(1024, 8) void attn_kernel(const float* __restrict__ Eq,
                                                       const float* __restrict__ Ekt,
                                                       const _Float16* __restrict__ Vh,
                                                       const float* __restrict__ wv,
                                                       float* __restrict__ out) {
    __shared__ __align__(16) unsigned sc[TQ * 1028];   // 32.9 KB: P hi/lo fp16
    __shared__ float wsum[16 * TQ];

    int tid = threadIdx.x;
    int blk = blockIdx.x;
    // XCD swizzle: blk%8 = XCD; batch b pinned to XCDs {2b,2b+1}.
    int b = (blk & 7) >> 1;
    int tile = (blk >> 3) * 2 + (blk & 1);   // 0..127, bijective per batch
    int qbase = tile * TQ;

    // ---- score phase: thread owns k = tid; q-pairs packed as float2 ----
    const float* kb = Ekt + (size_t)b * Hh * Kn;
    const float* qp = Eq + (size_t)(b * Qn + qbase) * Hh;
    const float4* wv4 = (const float4*)wv;
    floatx2 s2[TQ / 2];
    #pragma unroll
    for (int i = 0; i < TQ / 2; ++i) { s2[i].x = 0.f; s2[i].y = 0.f; }

    float e0 = kb[0 * Kn + tid];
    float e1 = kb[1 * Kn + tid];
    float e2 = kb[2 * Kn + tid];
    float e3 = kb[3 * Kn + tid];
    floatx2 one2 = mk2(1.f, 1.f);
    for (int h4 = 0; h4 < Hh / 4; ++h4) {
        float n0, n1, n2, n3;
        if (h4 < Hh / 4 - 1) {                 // prefetch next iteration
            const float* kn = kb + (h4 + 1) * 4 * Kn;
            n0 = kn[0 * Kn + tid];
            n1 = kn[1 * Kn + tid];
            n2 = kn[2 * Kn + tid];
            n3 = kn[3 * Kn + tid];
        }
        float4 w4 = wv4[h4];                            // uniform -> s_load
        floatx2 e0s = mk2(e0, e0), e1s = mk2(e1, e1);
        floatx2 e2s = mk2(e2, e2), e3s = mk2(e3, e3);
        floatx2 wx = mk2(w4.x, w4.x), wy = mk2(w4.y, w4.y);
        floatx2 wz = mk2(w4.z, w4.z), ww = mk2(w4.w, w4.w);
        #pragma unroll
        for (int qq = 0; qq < TQ; qq += 2) {
            float4 qva = *(const float4*)(qp + qq * Hh + h4 * 4);        // s_load
            float4 qvb = *(const float4*)(qp + (qq + 1) * Hh + h4 * 4);  // s_load
            floatx2 A = fma2(mk2(qva.x, qvb.x), e0s, one2);
            floatx2 B = fma2(mk2(qva.y, qvb.y), e1s, one2);
            floatx2 C = fma2(mk2(qva.z, qvb.z), e2s, one2);
            floatx2 D = fma2(mk2(qva.w, qvb.w), e3s, one2);
            floatx2 AB = A * B;
            floatx2 CD = C * D;
            floatx2 ABCD = AB * CD;
            floatx2 NAB = fma2(wx, B, wy * A);
            floatx2 NCD = fma2(wz, D, ww * C);
            floatx2 NUM = fma2(NCD, AB, NAB * CD);
            floatx2 R = mk2(__builtin_amdgcn_rcpf(ABCD.x),
                            __builtin_amdgcn_rcpf(ABCD.y));
            s2[qq >> 1] = fma2(NUM, R, s2[qq >> 1]);
        }
        e0 = n0; e1 = n1; e2 = n2; e3 = n3;
    }

    int wave = tid >> 6, lane = tid & 63;
    // ---- V prefetch for kt=0: P-independent, hides under exp/pack/barrier ----
    size_t vb0 = (((size_t)(b * 32) * 16 + wave) * 512) + (size_t)lane * 8;
    half8 vcur = *(const half8*)(Vh + vb0);

    // p = exp(-2s); write fp16 hi/lo; per-q wave partials (fp32 p).
    _Float16* sp = (_Float16*)sc;
    float part[TQ];
    #pragma unroll
    for (int q = 0; q < TQ; ++q) {
        float sq = (q & 1) ? s2[q >> 1].y : s2[q >> 1].x;
        float p = __expf(-2.f * sq);
        part[q] = p;
        _Float16 hs = (_Float16)p;
        sp[q * 2056 + tid] = hs;
        sp[q * 2056 + 1024 + tid] = (_Float16)(p - (float)hs);
    }

    #pragma unroll
    for (int q = 0; q < TQ; ++q) {
        #pragma unroll
        for (int off = 32; off >= 1; off >>= 1)
            part[q] += __shfl_xor(part[q], off, 64);
    }
    if (lane == 0) {
        #pragma unroll
        for (int q = 0; q < TQ; ++q) wsum[wave * TQ + q] = part[q];
    }
    __syncthreads();

    // ---- AV via fp16 MFMA, software-pipelined V ----
    int qf = lane & 15, kc = lane >> 4;
    int qd = qf & (TQ - 1);
    floatx4 acc = {0.f, 0.f, 0.f, 0.f};
    const char* scb = (const char*)sc + qd * 4112 + kc * 16;
    #pragma unroll 2
    for (int kt = 0; kt < 31; ++kt) {
        half8 vnext = *(const half8*)(Vh + vb0 + (size_t)(kt + 1) * 8192);
        half8 bhi = *(const half8*)(scb + kt * 64);
        half8 blo = *(const half8*)(scb + 2048 + kt * 64);
        acc = __builtin_amdgcn_mfma_f32_16x16x32_f16(vcur, bhi, acc, 0, 0, 0);
        acc = __builtin_amdgcn_mfma_f32_16x16x32_f16(vcur, blo, acc, 0, 0, 0);
        vcur = vnext;
    }
    {
        half8 bhi = *(const half8*)(scb + 31 * 64);
        half8 blo = *(const half8*)(scb + 2048 + 31 * 64);
        acc = __builtin_amdgcn_mfma_f32_16x16x32_f16(vcur, bhi, acc, 0, 0, 0);
        acc = __builtin_amdgcn_mfma_f32_16x16x32_f16(vcur, blo, acc, 0, 0, 0);
    }
    if (qf < TQ) {
        float vsum = 0.f;
        #pragma unroll
        for (int w = 0; w < 16; ++w) vsum += wsum[w * TQ + qd];
        float r = 1.f / vsum;
        float* ob = out + ((size_t)(b * Qn + qbase + qf)) * Dv + wave * 16 + kc * 4;
        float4 o = { acc[0] * r, acc[1] * r, acc[2] * r, acc[3] * r };
        *(float4*)ob = o;
    }
}

extern "C" void kernel_launch(void* const* d_in, const int* in_sizes, int n_in,
                              void* d_out, int out_size, void* d_ws, size_t ws_size,
                              hipStream_t stream) {
    const float* queries = (const float*)d_in[0];
    const float* keys    = (const float*)d_in[1];
    const float* values  = (const float*)d_in[2];
    const float* W_q     = (const float*)d_in[3];
    const float* W_k     = (const float*)d_in[4];
    const float* w_v     = (const float*)d_in[5];
    float* out = (float*)d_out;

    float* Eq  = (float*)d_ws;                    // [B*Q, H]      1 MB
    float* Ekt = Eq + Bn * Qn * Hh;               // [B, H, K]     1 MB
    _Float16* Vh = (_Float16*)(Ekt + Bn * Kn * Hh); // frag-order  2 MB

    prep_kernel<<<640, 256, 0, stream>>>(queries, W_q, keys, W_k, values,
                                         Eq, Ekt, Vh);
    attn_kernel<<<Bn * (Qn / TQ), 1024, 0, stream>>>(Eq, Ekt, Vh, w_v, out);
}

// Round 5
// 109.322 us; speedup vs baseline: 1.1527x; 1.0079x over previous
//
#include <hip/hip_runtime.h>

#define Bn 4
#define Qn 1024
#define Kn 1024
#define Dd 256
#define Hh 64
#define Dv 256
#define TQ 16

typedef __attribute__((ext_vector_type(8))) short short8;
typedef __attribute__((ext_vector_type(8))) _Float16 half8;
typedef __attribute__((ext_vector_type(4))) float floatx4;
typedef __attribute__((ext_vector_type(2))) float floatx2;

__device__ __forceinline__ floatx2 fma2(floatx2 a, floatx2 b, floatx2 c) {
    return __builtin_elementwise_fma(a, b, c);
}
__device__ __forceinline__ floatx2 mk2(float x, float y) {
    floatx2 r; r.x = x; r.y = y; return r;
}

__device__ __forceinline__ short f32_to_bf16(float x) {
    unsigned u = __float_as_uint(x);
    unsigned r = u + 0x7fffu + ((u >> 16) & 1u);   // RNE
    return (short)(r >> 16);
}
__device__ __forceinline__ float bf16_to_f32(short h) {
    return __uint_as_float(((unsigned)(unsigned short)h) << 16);
}

// Fused prep v7 (unchanged from R21): fully LDS-free / barrier-free.
//  blocks 0..511  : proj. side=blk>>8, row-tile=(blk&255)*16. Wave ct=w
//                   owns a 16x16 output tile: 16 b128 X loads + 64 scalar
//                   W loads (its 16-col slice), split-bf16, 24 MFMA,
//                   exp-fold epilogue. No sync -> waves run free.
//  blocks 512..639: V -> fp16 A-frag swizzle, direct gather (32 scalar
//                   loads, 4 lines/instr), 4 b128 stores. No sync.
// 640 blocks = 2.5 waves/SIMD of barrier-less latency overlap.
__global__ __launch_bounds__(256) void prep_kernel(const float* __restrict__ Xq,
                                                   const float* __restrict__ Wq,
                                                   const float* __restrict__ Xk,
                                                   const float* __restrict__ Wk,
                                                   const float* __restrict__ V,
                                                   float* __restrict__ Eq,
                                                   float* __restrict__ Ekt,
                                                   _Float16* __restrict__ Vh) {
    int t = threadIdx.x;
    int wave = t >> 6, l = t & 63;
    if (blockIdx.x < 512) {
        int side = blockIdx.x >> 8;              // 0: q, 1: k
        int r0 = (blockIdx.x & 255) * 16;        // row tile within side
        int ct = wave;                           // 16-col slice of H
        const float* X = side ? Xk : Xq;
        const float* W = side ? Wk : Wq;
        // ---- X loads (issued first, all in flight) ----
        const float* xrow = X + (size_t)(r0 + (l & 15)) * Dd + (l >> 4) * 8;
        floatx4 xa[8], xb[8];
        #pragma unroll
        for (int kt = 0; kt < 8; ++kt) {
            xa[kt] = *(const floatx4*)(xrow + kt * 32);
            xb[kt] = *(const floatx4*)(xrow + kt * 32 + 4);
        }
        // ---- W slice gather: 64 scalar loads, 4x64B lines per instr ----
        float wraw[8][8];
        #pragma unroll
        for (int kt = 0; kt < 8; ++kt) {
            const float* wp = W + (size_t)(kt * 32 + (l >> 4) * 8) * Hh + ct * 16 + (l & 15);
            #pragma unroll
            for (int j = 0; j < 8; ++j) wraw[kt][j] = wp[j * Hh];
        }
        // ---- split-bf16 fragments ----
        short8 ah[8], al[8], wh[8], wl[8];
        #pragma unroll
        for (int kt = 0; kt < 8; ++kt) {
            #pragma unroll
            for (int j = 0; j < 4; ++j) {
                short hs = f32_to_bf16(xa[kt][j]);
                ah[kt][j] = hs;
                al[kt][j] = f32_to_bf16(xa[kt][j] - bf16_to_f32(hs));
                short hs2 = f32_to_bf16(xb[kt][j]);
                ah[kt][j + 4] = hs2;
                al[kt][j + 4] = f32_to_bf16(xb[kt][j] - bf16_to_f32(hs2));
            }
            #pragma unroll
            for (int j = 0; j < 8; ++j) {
                short hs = f32_to_bf16(wraw[kt][j]);
                wh[kt][j] = hs;
                wl[kt][j] = f32_to_bf16(wraw[kt][j] - bf16_to_f32(hs));
            }
        }
        floatx4 acc = {0.f, 0.f, 0.f, 0.f};
        #pragma unroll
        for (int kt = 0; kt < 8; ++kt) {
            acc = __builtin_amdgcn_mfma_f32_16x16x32_bf16(ah[kt], wh[kt], acc, 0, 0, 0);
            acc = __builtin_amdgcn_mfma_f32_16x16x32_bf16(al[kt], wh[kt], acc, 0, 0, 0);
            acc = __builtin_amdgcn_mfma_f32_16x16x32_bf16(ah[kt], wl[kt], acc, 0, 0, 0);
        }
        // ---- epilogue: exp-fold and store ----
        int h = ct * 16 + (l & 15);
        float e0 = __expf(2.f * acc[0]);
        float e1 = __expf(2.f * acc[1]);
        float e2 = __expf(2.f * acc[2]);
        float e3 = __expf(2.f * acc[3]);
        int row0g = r0 + (l >> 4) * 4;           // reg i -> consecutive rows
        if (!side) {
            Eq[(size_t)(row0g + 0) * Hh + h] = e0;
            Eq[(size_t)(row0g + 1) * Hh + h] = e1;
            Eq[(size_t)(row0g + 2) * Hh + h] = e2;
            Eq[(size_t)(row0g + 3) * Hh + h] = e3;
        } else {
            int b = row0g >> 10, k0 = row0g & 1023;
            float4 o = { e0, e1, e2, e3 };
            *(float4*)(Ekt + ((size_t)(b * Hh + h)) * Kn + k0) = o;  // 16 full lines/instr
        }
    } else {
        int vblk = blockIdx.x - 512;
        int b = vblk >> 5;
        int kt = vblk & 31;
        const float* Vg = V + ((size_t)(b * Kn + kt * 32 + (l >> 4) * 8)) * Dv + (l & 15);
        #pragma unroll
        for (int p = 0; p < 4; ++p) {
            int nt = wave * 4 + p;
            const float* vp = Vg + nt * 16;
            half8 hv;
            #pragma unroll
            for (int j = 0; j < 8; ++j)
                hv[j] = (_Float16)vp[(size_t)j * Dv];
            size_t base = (((size_t)(b * 32 + kt) * 16 + nt) * 512) + (size_t)l * 8;
            *(half8*)(Vh + base) = hv;
        }
    }
}

// score(q,k) = W_sum - 2*sum_h w_h/(Eq_h*Ek_h+1); W_sum cancels in softmax.
// R22: TQ back to 16 (grid 256, 1 block/CU). R2 showed TQ8's extra blocks
// cost ~4us in doubled L2 traffic (Ekt 64->128MB, V 128->256MB) that the
// higher occupancy never recovered. Kept from R20/R21: fp16 split-P AV
// (2 MFMAs/kt), V(kt=0) prefetch under exp/pack, software-pipelined V in
// the AV loop, single barrier + per-thread finalize. Score math unchanged.
__global__ __launch_bounds__(1024, 4) void attn_kernel(const float* __restrict__ Eq,
                                                       const float* __restrict__ Ekt,
                                                       const _Float16* __restrict__ Vh,
                                                       const float* __restrict__ wv,
                                                       float* __restrict__ out) {
    __shared__ __align__(16) unsigned sc[TQ * 1028];   // 65.8 KB: P hi/lo fp16
    __shared__ float wsum[16 * TQ];

    int tid = threadIdx.x;
    int blk = blockIdx.x;
    // XCD swizzle: blk%8 = XCD; batch b pinned to XCDs {2b,2b+1}.
    int b = (blk & 7) >> 1;
    int tile = (blk >> 3) * 2 + (blk & 1);   // 0..63, bijective per batch
    int qbase = tile * TQ;

    // ---- score phase: thread owns k = tid; q-pairs packed as float2 ----
    const float* kb = Ekt + (size_t)b * Hh * Kn;
    const float* qp = Eq + (size_t)(b * Qn + qbase) * Hh;
    const float4* wv4 = (const float4*)wv;
    floatx2 s2[TQ / 2];
    #pragma unroll
    for (int i = 0; i < TQ / 2; ++i) { s2[i].x = 0.f; s2[i].y = 0.f; }

    float e0 = kb[0 * Kn + tid];
    float e1 = kb[1 * Kn + tid];
    float e2 = kb[2 * Kn + tid];
    float e3 = kb[3 * Kn + tid];
    floatx2 one2 = mk2(1.f, 1.f);
    for (int h4 = 0; h4 < Hh / 4; ++h4) {
        float n0, n1, n2, n3;
        if (h4 < Hh / 4 - 1) {                 // prefetch next iteration
            const float* kn = kb + (h4 + 1) * 4 * Kn;
            n0 = kn[0 * Kn + tid];
            n1 = kn[1 * Kn + tid];
            n2 = kn[2 * Kn + tid];
            n3 = kn[3 * Kn + tid];
        }
        float4 w4 = wv4[h4];                            // uniform -> s_load
        floatx2 e0s = mk2(e0, e0), e1s = mk2(e1, e1);
        floatx2 e2s = mk2(e2, e2), e3s = mk2(e3, e3);
        floatx2 wx = mk2(w4.x, w4.x), wy = mk2(w4.y, w4.y);
        floatx2 wz = mk2(w4.z, w4.z), ww = mk2(w4.w, w4.w);
        #pragma unroll
        for (int qq = 0; qq < TQ; qq += 2) {
            float4 qva = *(const float4*)(qp + qq * Hh + h4 * 4);        // s_load
            float4 qvb = *(const float4*)(qp + (qq + 1) * Hh + h4 * 4);  // s_load
            floatx2 A = fma2(mk2(qva.x, qvb.x), e0s, one2);
            floatx2 B = fma2(mk2(qva.y, qvb.y), e1s, one2);
            floatx2 C = fma2(mk2(qva.z, qvb.z), e2s, one2);
            floatx2 D = fma2(mk2(qva.w, qvb.w), e3s, one2);
            floatx2 AB = A * B;
            floatx2 CD = C * D;
            floatx2 ABCD = AB * CD;
            floatx2 NAB = fma2(wx, B, wy * A);
            floatx2 NCD = fma2(wz, D, ww * C);
            floatx2 NUM = fma2(NCD, AB, NAB * CD);
            floatx2 R = mk2(__builtin_amdgcn_rcpf(ABCD.x),
                            __builtin_amdgcn_rcpf(ABCD.y));
            s2[qq >> 1] = fma2(NUM, R, s2[qq >> 1]);
        }
        e0 = n0; e1 = n1; e2 = n2; e3 = n3;
    }

    int wave = tid >> 6, lane = tid & 63;
    // ---- V prefetch for kt=0: P-independent, hides under exp/pack/barrier ----
    size_t vb0 = (((size_t)(b * 32) * 16 + wave) * 512) + (size_t)lane * 8;
    half8 vcur = *(const half8*)(Vh + vb0);

    // p = exp(-2s); write fp16 hi/lo; per-q wave partials (fp32 p).
    _Float16* sp = (_Float16*)sc;
    float part[TQ];
    #pragma unroll
    for (int q = 0; q < TQ; ++q) {
        float sq = (q & 1) ? s2[q >> 1].y : s2[q >> 1].x;
        float p = __expf(-2.f * sq);
        part[q] = p;
        _Float16 hs = (_Float16)p;
        sp[q * 2056 + tid] = hs;
        sp[q * 2056 + 1024 + tid] = (_Float16)(p - (float)hs);
    }

    #pragma unroll
    for (int q = 0; q < TQ; ++q) {
        #pragma unroll
        for (int off = 32; off >= 1; off >>= 1)
            part[q] += __shfl_xor(part[q], off, 64);
    }
    if (lane == 0) {
        #pragma unroll
        for (int q = 0; q < TQ; ++q) wsum[wave * TQ + q] = part[q];
    }
    __syncthreads();

    // ---- AV via fp16 MFMA, software-pipelined V; wave owns ntile = wave ----
    int qf = lane & 15, kc = lane >> 4;
    floatx4 acc = {0.f, 0.f, 0.f, 0.f};
    const char* scb = (const char*)sc + qf * 4112 + kc * 16;
    #pragma unroll 2
    for (int kt = 0; kt < 31; ++kt) {
        half8 vnext = *(const half8*)(Vh + vb0 + (size_t)(kt + 1) * 8192);
        half8 bhi = *(const half8*)(scb + kt * 64);
        half8 blo = *(const half8*)(scb + 2048 + kt * 64);
        acc = __builtin_amdgcn_mfma_f32_16x16x32_f16(vcur, bhi, acc, 0, 0, 0);
        acc = __builtin_amdgcn_mfma_f32_16x16x32_f16(vcur, blo, acc, 0, 0, 0);
        vcur = vnext;
    }
    {
        half8 bhi = *(const half8*)(scb + 31 * 64);
        half8 blo = *(const half8*)(scb + 2048 + 31 * 64);
        acc = __builtin_amdgcn_mfma_f32_16x16x32_f16(vcur, bhi, acc, 0, 0, 0);
        acc = __builtin_amdgcn_mfma_f32_16x16x32_f16(vcur, blo, acc, 0, 0, 0);
    }
    {
        float vsum = 0.f;
        #pragma unroll
        for (int w = 0; w < 16; ++w) vsum += wsum[w * TQ + qf];
        float r = 1.f / vsum;
        float* ob = out + ((size_t)(b * Qn + qbase + qf)) * Dv + wave * 16 + kc * 4;
        float4 o = { acc[0] * r, acc[1] * r, acc[2] * r, acc[3] * r };
        *(float4*)ob = o;
    }
}

extern "C" void kernel_launch(void* const* d_in, const int* in_sizes, int n_in,
                              void* d_out, int out_size, void* d_ws, size_t ws_size,
                              hipStream_t stream) {
    const float* queries = (const float*)d_in[0];
    const float* keys    = (const float*)d_in[1];
    const float* values  = (const float*)d_in[2];
    const float* W_q     = (const float*)d_in[3];
    const float* W_k     = (const float*)d_in[4];
    const float* w_v     = (const float*)d_in[5];
    float* out = (float*)d_out;

    float* Eq  = (float*)d_ws;                    // [B*Q, H]      1 MB
    float* Ekt = Eq + Bn * Qn * Hh;               // [B, H, K]     1 MB
    _Float16* Vh = (_Float16*)(Ekt + Bn * Kn * Hh); // frag-order  2 MB

    prep_kernel<<<640, 256, 0, stream>>>(queries, W_q, keys, W_k, values,
                                         Eq, Ekt, Vh);
    attn_kernel<<<Bn * (Qn / TQ), 1024, 0, stream>>>(Eq, Ekt, Vh, w_v, out);
}